// Round 1
// baseline (1367.105 us; speedup 1.0000x reference)
//
#include <hip/hip_runtime.h>

#define NNODES 100000
#define NEDGES 3200000
#define ETOT   (NEDGES + NNODES)
#define NEG_SLOPE 0.2f

// edge e in [0, NEDGES): src = ei[e], dst = ei[NEDGES+e]
// edge e in [NEDGES, ETOT): self-loop, src = dst = e - NEDGES
__device__ __forceinline__ void edge_sd(int e, const int* __restrict__ ei, int& s, int& d) {
    if (e < NEDGES) { s = ei[e]; d = ei[NEDGES + e]; }
    else            { s = e - NEDGES; d = s; }
}

__device__ __forceinline__ float lrelu(float v) {
    return v > 0.0f ? v : NEG_SLOPE * v;
}

// Layer 1 node kernel: h = x @ W1 (2->16), as = h.a_src, ad = h.a_dst
__global__ void l1_node(const float* __restrict__ x, const float* __restrict__ W1,
                        const float* __restrict__ a_s, const float* __restrict__ a_d,
                        float* __restrict__ h, float* __restrict__ as_, float* __restrict__ ad_) {
    int n = blockIdx.x * blockDim.x + threadIdx.x;
    if (n >= NNODES) return;
    float x0 = x[2 * n], x1 = x[2 * n + 1];
    float s = 0.f, d = 0.f;
#pragma unroll
    for (int f = 0; f < 16; ++f) {
        float hf = x0 * W1[f] + x1 * W1[16 + f];
        h[n * 16 + f] = hf;
        s += hf * a_s[f];
        d += hf * a_d[f];
    }
    as_[n] = s; ad_[n] = d;
}

// Layer 2 node kernel: h = g @ W2 (16->64), as = h.a_src, ad = h.a_dst
__global__ void l2_node(const float* __restrict__ g, const float* __restrict__ W2,
                        const float* __restrict__ a_s, const float* __restrict__ a_d,
                        float* __restrict__ h, float* __restrict__ as_, float* __restrict__ ad_) {
    int n = blockIdx.x * blockDim.x + threadIdx.x;
    if (n >= NNODES) return;
    float gi[16];
#pragma unroll
    for (int k = 0; k < 16; ++k) gi[k] = g[n * 16 + k];
    float s = 0.f, d = 0.f;
#pragma unroll 4
    for (int f = 0; f < 64; ++f) {
        float hf = 0.f;
#pragma unroll
        for (int k = 0; k < 16; ++k) hf += gi[k] * W2[k * 64 + f];
        h[n * 64 + f] = hf;
        s += hf * a_s[f];
        d += hf * a_d[f];
    }
    as_[n] = s; ad_[n] = d;
}

// Edge pass 1: softmax denominator s[dst] += exp(lrelu(as[src] + ad[dst]))
__global__ void edge_sum(const int* __restrict__ ei, const float* __restrict__ as_,
                         const float* __restrict__ ad_, float* __restrict__ ssum) {
    int e = blockIdx.x * blockDim.x + threadIdx.x;
    if (e >= ETOT) return;
    int s, d; edge_sd(e, ei, s, d);
    float v = lrelu(as_[s] + ad_[d]);
    atomicAdd(&ssum[d], expf(v));
}

// Edge pass 2: acc[dst,f] += (exp(e)/s[dst]) * h[src,f]; one thread per (edge, feature)
template <int LOGF>
__global__ void edge_scatter(const int* __restrict__ ei, const float* __restrict__ as_,
                             const float* __restrict__ ad_, const float* __restrict__ ssum,
                             const float* __restrict__ h, float* __restrict__ acc) {
    const int F = 1 << LOGF;
    int idx = blockIdx.x * blockDim.x + threadIdx.x;
    int e = idx >> LOGF;
    if (e >= ETOT) return;
    int f = idx & (F - 1);
    int s, d; edge_sd(e, ei, s, d);
    float v = lrelu(as_[s] + ad_[d]);
    float w = expf(v) / ssum[d];
    atomicAdd(&acc[d * F + f], w * h[s * F + f]);
}

// Finalize: out = relu(acc + b), in place allowed (out may == acc)
template <int LOGF>
__global__ void finalize(const float* __restrict__ acc, const float* __restrict__ b,
                         float* __restrict__ out) {
    const int F = 1 << LOGF;
    int idx = blockIdx.x * blockDim.x + threadIdx.x;
    if (idx >= NNODES * F) return;
    int f = idx & (F - 1);
    float v = acc[idx] + b[f];
    out[idx] = v > 0.f ? v : 0.f;
}

extern "C" void kernel_launch(void* const* d_in, const int* in_sizes, int n_in,
                              void* d_out, int out_size, void* d_ws, size_t ws_size,
                              hipStream_t stream) {
    const float* x     = (const float*)d_in[0];
    const int*   ei    = (const int*)  d_in[1];
    const float* W1    = (const float*)d_in[2];
    const float* as1w  = (const float*)d_in[3];
    const float* ad1w  = (const float*)d_in[4];
    const float* b1    = (const float*)d_in[5];
    const float* W2    = (const float*)d_in[6];
    const float* as2w  = (const float*)d_in[7];
    const float* ad2w  = (const float*)d_in[8];
    const float* b2    = (const float*)d_in[9];
    float* out = (float*)d_out;

    // Workspace layout (floats)
    float* ws = (float*)d_ws;
    float* h1   = ws;                    // N*16
    float* as1  = h1  + (size_t)NNODES * 16;   // N
    float* ad1  = as1 + NNODES;                // N
    float* s1   = ad1 + NNODES;                // N
    float* acc1 = s1  + NNODES;                // N*16 (becomes g after finalize)
    float* h2   = acc1 + (size_t)NNODES * 16;  // N*64
    float* as2  = h2  + (size_t)NNODES * 64;   // N
    float* ad2  = as2 + NNODES;                // N
    float* s2   = ad2 + NNODES;                // N

    const int B = 256;

    // zero the accumulators (ws/d_out are poisoned before every call)
    hipMemsetAsync(s1,   0, sizeof(float) * NNODES, stream);
    hipMemsetAsync(acc1, 0, sizeof(float) * NNODES * 16, stream);
    hipMemsetAsync(s2,   0, sizeof(float) * NNODES, stream);
    hipMemsetAsync(out,  0, sizeof(float) * NNODES * 64, stream);

    // ---- Layer 1 ----
    l1_node<<<(NNODES + B - 1) / B, B, 0, stream>>>(x, W1, as1w, ad1w, h1, as1, ad1);
    edge_sum<<<(ETOT + B - 1) / B, B, 0, stream>>>(ei, as1, ad1, s1);
    {
        int total = ETOT * 16;
        edge_scatter<4><<<(total + B - 1) / B, B, 0, stream>>>(ei, as1, ad1, s1, h1, acc1);
    }
    finalize<4><<<(NNODES * 16 + B - 1) / B, B, 0, stream>>>(acc1, b1, acc1);  // acc1 -> g in place

    // ---- Layer 2 ----
    l2_node<<<(NNODES + B - 1) / B, B, 0, stream>>>(acc1, W2, as2w, ad2w, h2, as2, ad2);
    edge_sum<<<(ETOT + B - 1) / B, B, 0, stream>>>(ei, as2, ad2, s2);
    {
        long long total = (long long)ETOT * 64;
        int blocks = (int)((total + B - 1) / B);
        edge_scatter<6><<<blocks, B, 0, stream>>>(ei, as2, ad2, s2, h2, out);
    }
    finalize<6><<<(NNODES * 64 + B - 1) / B, B, 0, stream>>>(out, b2, out);
}

// Round 3
// 908.050 us; speedup vs baseline: 1.5055x; 1.5055x over previous
//
#include <hip/hip_runtime.h>

#define NNODES 100000
#define NEDGES 3200000
#define ETOT   (NEDGES + NNODES)
#define NEG_SLOPE 0.2f

// edge e in [0, NEDGES): src = ei[e], dst = ei[NEDGES+e]
// edge e in [NEDGES, ETOT): self-loop, src = dst = e - NEDGES
__device__ __forceinline__ void edge_sd(int e, const int* __restrict__ ei, int& s, int& d) {
    if (e < NEDGES) { s = ei[e]; d = ei[NEDGES + e]; }
    else            { s = e - NEDGES; d = s; }
}

__device__ __forceinline__ float lrelu(float v) {
    return v > 0.0f ? v : NEG_SLOPE * v;
}

// ---------------- CSR build (unchanged from round 2 — under test) ----------------

__global__ void hist_kernel(const int* __restrict__ ei, int* __restrict__ cnt) {
    int e = blockIdx.x * blockDim.x + threadIdx.x;
    if (e >= ETOT) return;
    int s, d; edge_sd(e, ei, s, d);
    atomicAdd(&cnt[d], 1);
}

// single-block exclusive scan over 100k ints (1024 threads, ~98 elems each)
__global__ void scan_kernel(const int* __restrict__ cnt, int* __restrict__ row_start) {
    __shared__ int sums[1024];
    const int CH = (NNODES + 1023) / 1024;  // 98
    int t = threadIdx.x;
    int lo = t * CH;
    int hi = lo + CH; if (hi > NNODES) hi = NNODES; if (lo > NNODES) lo = NNODES;
    int s = 0;
    for (int i = lo; i < hi; ++i) s += cnt[i];
    sums[t] = s;
    __syncthreads();
    for (int off = 1; off < 1024; off <<= 1) {
        int u = (t >= off) ? sums[t - off] : 0;
        __syncthreads();
        sums[t] += u;
        __syncthreads();
    }
    int run = sums[t] - s;  // exclusive offset of this thread's chunk
    for (int i = lo; i < hi; ++i) { row_start[i] = run; run += cnt[i]; }
    if (t == 0) row_start[NNODES] = ETOT;
}

__global__ void copy_cursor(const int* __restrict__ row_start, int* __restrict__ cursor) {
    int i = blockIdx.x * blockDim.x + threadIdx.x;
    if (i < NNODES) cursor[i] = row_start[i];
}

__global__ void csr_scatter(const int* __restrict__ ei, int* __restrict__ cursor,
                            int* __restrict__ csr_src) {
    int e = blockIdx.x * blockDim.x + threadIdx.x;
    if (e >= ETOT) return;
    int s, d; edge_sd(e, ei, s, d);
    int slot = atomicAdd(&cursor[d], 1);
    csr_src[slot] = s;
}

// ---------------- node transforms (unchanged from round 1 — proven) ----------------

__global__ void l1_node(const float* __restrict__ x, const float* __restrict__ W1,
                        const float* __restrict__ a_s, const float* __restrict__ a_d,
                        float* __restrict__ h, float* __restrict__ as_, float* __restrict__ ad_) {
    int n = blockIdx.x * blockDim.x + threadIdx.x;
    if (n >= NNODES) return;
    float x0 = x[2 * n], x1 = x[2 * n + 1];
    float s = 0.f, d = 0.f;
#pragma unroll
    for (int f = 0; f < 16; ++f) {
        float hf = x0 * W1[f] + x1 * W1[16 + f];
        h[n * 16 + f] = hf;
        s += hf * a_s[f];
        d += hf * a_d[f];
    }
    as_[n] = s; ad_[n] = d;
}

__global__ void l2_node(const float* __restrict__ g, const float* __restrict__ W2,
                        const float* __restrict__ a_s, const float* __restrict__ a_d,
                        float* __restrict__ h, float* __restrict__ as_, float* __restrict__ ad_) {
    int n = blockIdx.x * blockDim.x + threadIdx.x;
    if (n >= NNODES) return;
    float gi[16];
#pragma unroll
    for (int k = 0; k < 16; ++k) gi[k] = g[n * 16 + k];
    float s = 0.f, d = 0.f;
#pragma unroll 4
    for (int f = 0; f < 64; ++f) {
        float hf = 0.f;
#pragma unroll
        for (int k = 0; k < 16; ++k) hf += gi[k] * W2[k * 64 + f];
        h[n * 64 + f] = hf;
        s += hf * a_s[f];
        d += hf * a_d[f];
    }
    as_[n] = s; ad_[n] = d;
}

// ---------------- gather aggregation: scalar edge loop, ZERO cross-lane ops ----------------

// F=64: one wave per dst node; lane = feature. Every lane redundantly walks the
// edge list (same-address loads broadcast); ss is replicated in all lanes.
__global__ void agg64(const int* __restrict__ row_start, const int* __restrict__ csr_src,
                      const float* __restrict__ as_, const float* __restrict__ ad_,
                      const float* __restrict__ h, const float* __restrict__ b,
                      float* __restrict__ out) {
    int wave = threadIdx.x >> 6;
    int lane = threadIdx.x & 63;
    int node = blockIdx.x * 4 + wave;
    if (node >= NNODES) return;
    int base = row_start[node], end = row_start[node + 1];
    float adv = ad_[node];
    float acc = 0.f, ss = 0.f;
#pragma unroll 4
    for (int i = base; i < end; ++i) {
        int sj = csr_src[i];
        float wj = expf(lrelu(as_[sj] + adv));
        ss += wj;
        acc += wj * h[(size_t)sj * 64 + lane];
    }
    float v = acc / ss + b[lane];
    out[(size_t)node * 64 + lane] = v > 0.f ? v : 0.f;
}

// F=16: one 16-lane group per dst node (4 nodes per wave). Same scalar pattern.
__global__ void agg16(const int* __restrict__ row_start, const int* __restrict__ csr_src,
                      const float* __restrict__ as_, const float* __restrict__ ad_,
                      const float* __restrict__ h, const float* __restrict__ b,
                      float* __restrict__ out) {
    int t = blockIdx.x * blockDim.x + threadIdx.x;
    int node = t >> 4;
    int f = t & 15;
    if (node >= NNODES) return;
    int base = row_start[node], end = row_start[node + 1];
    float adv = ad_[node];
    float acc = 0.f, ss = 0.f;
#pragma unroll 4
    for (int i = base; i < end; ++i) {
        int sj = csr_src[i];
        float wj = expf(lrelu(as_[sj] + adv));
        ss += wj;
        acc += wj * h[sj * 16 + f];
    }
    float v = acc / ss + b[f];
    out[node * 16 + f] = v > 0.f ? v : 0.f;
}

extern "C" void kernel_launch(void* const* d_in, const int* in_sizes, int n_in,
                              void* d_out, int out_size, void* d_ws, size_t ws_size,
                              hipStream_t stream) {
    const float* x     = (const float*)d_in[0];
    const int*   ei    = (const int*)  d_in[1];
    const float* W1    = (const float*)d_in[2];
    const float* as1w  = (const float*)d_in[3];
    const float* ad1w  = (const float*)d_in[4];
    const float* b1    = (const float*)d_in[5];
    const float* W2    = (const float*)d_in[6];
    const float* as2w  = (const float*)d_in[7];
    const float* ad2w  = (const float*)d_in[8];
    const float* b2    = (const float*)d_in[9];
    float* out = (float*)d_out;

    // ws layout (4-byte elems, ~40.4 MB):
    //   row_start[N+4] | cnt/cursor[N] | csr_src[ETOT] | hbuf[N*64] | asb[N] | adb[N]
    // hbuf reused: h1 (N*16) layer 1, h2 (N*64) layer 2. asb/adb reused per layer.
    // g (layer-1 output, N*16) lives in d_out; agg64 fully overwrites d_out afterwards.
    int* row_start = (int*)d_ws;
    int* cnt       = row_start + (NNODES + 4);   // doubles as cursor after scan
    int* csr_src   = cnt + NNODES;
    float* hbuf    = (float*)(csr_src + ETOT);
    float* asb     = hbuf + (size_t)NNODES * 64;
    float* adb     = asb + NNODES;
    float* g       = out;  // N*16 floats, dead before agg64 overwrites d_out

    const int B = 256;
    const int EB = (ETOT + B - 1) / B;
    const int NB = (NNODES + B - 1) / B;

    // ---- CSR build (shared by both layers) ----
    hipMemsetAsync(cnt, 0, sizeof(int) * NNODES, stream);
    hist_kernel<<<EB, B, 0, stream>>>(ei, cnt);
    scan_kernel<<<1, 1024, 0, stream>>>(cnt, row_start);
    copy_cursor<<<NB, B, 0, stream>>>(row_start, cnt);   // cnt becomes cursor
    csr_scatter<<<EB, B, 0, stream>>>(ei, cnt, csr_src);

    // ---- Layer 1 ----
    l1_node<<<NB, B, 0, stream>>>(x, W1, as1w, ad1w, hbuf, asb, adb);
    agg16<<<(NNODES * 16 + B - 1) / B, B, 0, stream>>>(row_start, csr_src, asb, adb, hbuf, b1, g);

    // ---- Layer 2 ----
    l2_node<<<NB, B, 0, stream>>>(g, W2, as2w, ad2w, hbuf, asb, adb);
    agg64<<<(NNODES + 3) / 4, B, 0, stream>>>(row_start, csr_src, asb, adb, hbuf, b2, out);
}